// Round 14
// baseline (134.594 us; speedup 1.0000x reference)
//
#include <hip/hip_runtime.h>
#include <math.h>

// Problem constants (B, N, F_IN, E_DIM, F, T) = (4, 64, 32, 32, 64, 3)
#define Bv   4
#define Nv   64
#define FIN  32
#define EDIM 32
#define Fv   64
#define NN   (Nv*Nv)
#define ZROW 256            // sentinel H row (always zero) for padded edges
#define SCOPE_AGENT __HIP_MEMORY_SCOPE_AGENT

typedef __bf16 bf16x8 __attribute__((ext_vector_type(8)));
typedef float  f32x4  __attribute__((ext_vector_type(4)));

__device__ __forceinline__ float sigmoidf_(float x) {
    return 1.f / (1.f + __expf(-x));
}

// ---------------------------------------------------------------------------
// One-time prep, fused: grid 768 x 64 threads.  (R9-proven + counter zeroing)
// ---------------------------------------------------------------------------
__global__ __launch_bounds__(64) void prep_kernel(
    const float* __restrict__ X, const float* __restrict__ W_embed,
    const float* __restrict__ b_embed, const float* __restrict__ A,
    const float* __restrict__ E, const float* __restrict__ W_edge,
    float* __restrict__ H0, float* __restrict__ H1,
    __bf16* __restrict__ Wf, __bf16* __restrict__ Ebf,
    int* __restrict__ ml_g, int* __restrict__ cnt_g,
    int* __restrict__ cnt2)
{
    const int blk  = blockIdx.x;
    const int lane = threadIdx.x;

    if (blk < 256) {                       // ---- W_edge fragments ----
        const int nt = blk;
        const int kb = (lane >> 4) * 8;
        const int c  = nt*16 + (lane & 15);
        bf16x8 v;
        #pragma unroll
        for (int t = 0; t < 8; ++t)
            v[t] = (__bf16)W_edge[(kb + t)*4096 + c];
        *(bf16x8*)(Wf + ((size_t)(nt*64 + lane))*8) = v;
        if (blk == 0) {                    // zero sentinel rows
            H0[ZROW*Fv + lane] = 0.f;
            H1[ZROW*Fv + lane] = 0.f;
        }
    } else if (blk < 512) {                // ---- edge list + E rows ----
        const int bn = blk - 256;
        const int b  = bn >> 6;
        const int n  = bn & 63;
        __shared__ int ml[Nv];
        const float av = A[b*NN + n*Nv + lane];
        const unsigned long long mk = __ballot(av != 0.f);
        const int cnt = (int)__popcll(mk);
        if (av != 0.f) {
            const int pos = (int)__popcll(mk & ((1ull << lane) - 1ull));
            ml[pos] = lane;
        }
        __syncthreads();
        ml_g[bn*64 + lane] = (lane < cnt) ? (b*Nv + ml[lane]) : ZROW;
        if (lane == 0) cnt_g[bn] = cnt;
        if (lane < 3)  cnt2[lane*256 + bn] = 0;   // reset round-r arrival ctr
        __bf16 row[EDIM];
        if (lane < cnt) {
            const float* er = E + ((size_t)(b*NN + n*Nv + ml[lane]))*EDIM;
            #pragma unroll
            for (int t = 0; t < 8; ++t) {
                const float4 x = *(const float4*)(er + 4*t);
                row[4*t  ] = (__bf16)x.x; row[4*t+1] = (__bf16)x.y;
                row[4*t+2] = (__bf16)x.z; row[4*t+3] = (__bf16)x.w;
            }
        } else {
            #pragma unroll
            for (int e = 0; e < EDIM; ++e) row[e] = (__bf16)0.f;
        }
        __bf16* dst = Ebf + ((size_t)(bn*64 + lane))*EDIM;
        #pragma unroll
        for (int t = 0; t < 4; ++t)
            *(bf16x8*)(dst + 8*t) = *(bf16x8*)(row + 8*t);
    } else {                               // ---- embed ----
        const int bn = blk - 512;
        __shared__ float xs[FIN];
        if (lane < FIN) xs[lane] = X[bn*FIN + lane];
        __syncthreads();
        float acc = b_embed[lane];
        #pragma unroll
        for (int k = 0; k < FIN; ++k)
            acc = fmaf(xs[k], W_embed[k*Fv + lane], acc);
        H0[bn*Fv + lane] = fmaxf(acc, 0.f);
    }
}

// ---------------------------------------------------------------------------
// Message body (R6/R9-proven math; agg published via agent-scope atomics).
// ---------------------------------------------------------------------------
template<int MTN>
__device__ __forceinline__ void msg_body(
    int bn, int qq, int w, int lane,
    const float* __restrict__ Hin, const __bf16* __restrict__ Wf,
    const float* __restrict__ b_edge, const __bf16* __restrict__ Ebf,
    const int* __restrict__ ml_g, float* __restrict__ agg_g)
{
    const int c16 = lane & 15;
    const int rg  = (lane >> 4) * 4;
    const int kb  = (lane >> 4) * 8;

    bf16x8 af[MTN];
    int4   ri[MTN];
    #pragma unroll
    for (int mt = 0; mt < MTN; ++mt) {
        af[mt] = *(const bf16x8*)(Ebf + ((size_t)(bn*64 + mt*16 + c16))*EDIM + kb);
        ri[mt] = *(const int4*)(ml_g + bn*64 + mt*16 + rg);
    }

    const int i0 = qq*8 + w*2;
    float p0 = 0.f, p1 = 0.f;

    #pragma unroll
    for (int u = 0; u < 4; ++u) {
        const int jc = u*16 + c16;
        float hu[MTN][4];
        #pragma unroll
        for (int mt = 0; mt < MTN; ++mt) {
            hu[mt][0] = Hin[ri[mt].x*Fv + jc];
            hu[mt][1] = Hin[ri[mt].y*Fv + jc];
            hu[mt][2] = Hin[ri[mt].z*Fv + jc];
            hu[mt][3] = Hin[ri[mt].w*Fv + jc];
        }
        #pragma unroll
        for (int ii = 0; ii < 2; ++ii) {
            const int nt = (i0 + ii)*4 + u;
            const bf16x8 bf = *(const bf16x8*)(Wf + ((size_t)(nt*64 + lane))*8);
            const float  be = b_edge[nt*16 + c16];
            f32x4 cb; cb[0] = be; cb[1] = be; cb[2] = be; cb[3] = be;
            float acc = 0.f;
            #pragma unroll
            for (int mt = 0; mt < MTN; ++mt) {
                f32x4 d = __builtin_amdgcn_mfma_f32_16x16x32_bf16(af[mt], bf, cb, 0, 0, 0);
                acc = fmaf(fmaxf(d[0], 0.f), hu[mt][0], acc);
                acc = fmaf(fmaxf(d[1], 0.f), hu[mt][1], acc);
                acc = fmaf(fmaxf(d[2], 0.f), hu[mt][2], acc);
                acc = fmaf(fmaxf(d[3], 0.f), hu[mt][3], acc);
            }
            if (ii == 0) p0 += acc; else p1 += acc;
        }
    }
    #pragma unroll
    for (int off = 32; off > 0; off >>= 1) {
        p0 += __shfl_xor(p0, off);
        p1 += __shfl_xor(p1, off);
    }
    if (lane == 0) {
        __hip_atomic_store(&agg_g[bn*Fv + i0],     p0, __ATOMIC_RELAXED, SCOPE_AGENT);
        __hip_atomic_store(&agg_g[bn*Fv + i0 + 1], p1, __ATOMIC_RELAXED, SCOPE_AGENT);
    }
}

// general single-node path (rare, cnt > 32): runtime mt loop
__device__ __forceinline__ void msg_general(
    int bn, int Mt, int qq, int w, int lane,
    const float* __restrict__ Hin, const __bf16* __restrict__ Wf,
    const float* __restrict__ b_edge, const __bf16* __restrict__ Ebf,
    const int* __restrict__ ml_g, float* __restrict__ agg_g)
{
    const int c16 = lane & 15;
    const int rg  = (lane >> 4) * 4;
    const int kb  = (lane >> 4) * 8;
    const int i0  = qq*8 + w*2;
    #pragma unroll
    for (int ii = 0; ii < 2; ++ii) {
        float part = 0.f;
        #pragma unroll 1
        for (int u = 0; u < 4; ++u) {
            const int jc = u*16 + c16;
            const int nt = (i0 + ii)*4 + u;
            const bf16x8 bf = *(const bf16x8*)(Wf + ((size_t)(nt*64 + lane))*8);
            const float  be = b_edge[nt*16 + c16];
            f32x4 cb; cb[0] = be; cb[1] = be; cb[2] = be; cb[3] = be;
            for (int mt = 0; mt < Mt; ++mt) {
                const bf16x8 a_ = *(const bf16x8*)(Ebf + ((size_t)(bn*64 + mt*16 + c16))*EDIM + kb);
                const int4 ri = *(const int4*)(ml_g + bn*64 + mt*16 + rg);
                f32x4 d = __builtin_amdgcn_mfma_f32_16x16x32_bf16(a_, bf, cb, 0, 0, 0);
                part = fmaf(fmaxf(d[0], 0.f), Hin[ri.x*Fv + jc], part);
                part = fmaf(fmaxf(d[1], 0.f), Hin[ri.y*Fv + jc], part);
                part = fmaf(fmaxf(d[2], 0.f), Hin[ri.z*Fv + jc], part);
                part = fmaf(fmaxf(d[3], 0.f), Hin[ri.w*Fv + jc], part);
            }
        }
        #pragma unroll
        for (int off = 32; off > 0; off >>= 1)
            part += __shfl_xor(part, off);
        if (lane == 0)
            __hip_atomic_store(&agg_g[bn*Fv + i0 + ii], part, __ATOMIC_RELAXED, SCOPE_AGENT);
    }
}

// ---------------------------------------------------------------------------
// Fused round: msg at full parallelism (grid (256,8)) + last-arriver GRU.
// The 8 blocks of node bn each publish agg slices (agent atomics), then
// fetch_add an arrival counter; the unique block seeing old==7 runs the
// in-block GRU (R8-validated body). No spinning -> deadlock-free.
// ---------------------------------------------------------------------------
__global__ __launch_bounds__(256) void round_kernel(
    const float* __restrict__ Hin, float* __restrict__ Hout,
    const __bf16* __restrict__ Wf, const float* __restrict__ b_edge,
    const __bf16* __restrict__ Ebf, const int* __restrict__ ml_g,
    const int* __restrict__ cnt_g,
    const float* __restrict__ gk, const float* __restrict__ grk,
    const float* __restrict__ gb, const float* __restrict__ grb,
    float* __restrict__ agg_g, int* __restrict__ cnt2)
{
    const int bn   = blockIdx.x;
    const int qq   = blockIdx.y;
    const int tid  = threadIdx.x;
    const int w    = tid >> 6;
    const int lane = tid & 63;

    // ---- msg phase (R9-proven) ----
    const int cnt = cnt_g[bn];
    const int Mt  = (cnt == 0) ? 1 : ((cnt + 15) >> 4);
    if (Mt <= 1)      msg_body<1>(bn, qq, w, lane, Hin, Wf, b_edge, Ebf, ml_g, agg_g);
    else if (Mt == 2) msg_body<2>(bn, qq, w, lane, Hin, Wf, b_edge, Ebf, ml_g, agg_g);
    else              msg_general(bn, Mt, qq, w, lane, Hin, Wf, b_edge, Ebf, ml_g, agg_g);

    // drain all lanes' atomic stores (syncthreads implies vmcnt(0) first)
    __syncthreads();

    __shared__ int old_sh;
    if (tid == 0)
        old_sh = __hip_atomic_fetch_add(&cnt2[bn], 1, __ATOMIC_ACQ_REL, SCOPE_AGENT);
    __syncthreads();
    if (old_sh != 7) return;               // not the last arriver

    // ---- GRU phase (last arriver only; R8-validated in-block body) ----
    __shared__ float h_old[Fv];
    __shared__ float aggs[Fv];
    __shared__ float h1[Fv];
    __shared__ float xg[3*Fv];
    __shared__ float hg[3*Fv];

    if (tid < Fv) {
        h_old[tid] = Hin[bn*Fv + tid];
        aggs[tid]  = __hip_atomic_load(&agg_g[bn*Fv + tid], __ATOMIC_RELAXED, SCOPE_AGENT);
    }
    __syncthreads();

    if (tid < 3*Fv) {                      // step 1: h=0, x=h_old
        float a0 = 0.f, a1 = 0.f, a2 = 0.f, a3 = 0.f;
        #pragma unroll
        for (int k = 0; k < 16; ++k) {
            a0 = fmaf(h_old[k],      gk[(k     )*192 + tid], a0);
            a1 = fmaf(h_old[k + 16], gk[(k + 16)*192 + tid], a1);
            a2 = fmaf(h_old[k + 32], gk[(k + 32)*192 + tid], a2);
            a3 = fmaf(h_old[k + 48], gk[(k + 48)*192 + tid], a3);
        }
        xg[tid] = gb[tid] + ((a0 + a1) + (a2 + a3));
    }
    __syncthreads();
    if (tid < Fv) {
        float z    = sigmoidf_(xg[tid]       + grb[tid]);
        float r    = sigmoidf_(xg[64 + tid]  + grb[64 + tid]);
        float cand = tanhf    (xg[128 + tid] + r * grb[128 + tid]);
        h1[tid] = (1.f - z) * cand;        // z*h + (1-z)*cand with h=0
    }
    __syncthreads();
    if (tid < 3*Fv) {                      // step 2: h=h1, x=agg
        float x0 = 0.f, x1 = 0.f, x2 = 0.f, x3 = 0.f;
        float y0 = 0.f, y1 = 0.f, y2 = 0.f, y3 = 0.f;
        #pragma unroll
        for (int k = 0; k < 16; ++k) {
            x0 = fmaf(aggs[k],      gk [(k     )*192 + tid], x0);
            x1 = fmaf(aggs[k + 16], gk [(k + 16)*192 + tid], x1);
            x2 = fmaf(aggs[k + 32], gk [(k + 32)*192 + tid], x2);
            x3 = fmaf(aggs[k + 48], gk [(k + 48)*192 + tid], x3);
            y0 = fmaf(h1[k],        grk[(k     )*192 + tid], y0);
            y1 = fmaf(h1[k + 16],   grk[(k + 16)*192 + tid], y1);
            y2 = fmaf(h1[k + 32],   grk[(k + 32)*192 + tid], y2);
            y3 = fmaf(h1[k + 48],   grk[(k + 48)*192 + tid], y3);
        }
        xg[tid] = gb[tid]  + ((x0 + x1) + (x2 + x3));
        hg[tid] = grb[tid] + ((y0 + y1) + (y2 + y3));
    }
    __syncthreads();
    if (tid < Fv) {
        float z    = sigmoidf_(xg[tid]       + hg[tid]);
        float r    = sigmoidf_(xg[64 + tid]  + hg[64 + tid]);
        float cand = tanhf    (xg[128 + tid] + r * hg[128 + tid]);
        Hout[bn*Fv + tid] = z * h1[tid] + (1.f - z) * cand;
    }
}

extern "C" void kernel_launch(void* const* d_in, const int* in_sizes, int n_in,
                              void* d_out, int out_size, void* d_ws, size_t ws_size,
                              hipStream_t stream)
{
    const float* X       = (const float*)d_in[0];
    const float* A       = (const float*)d_in[1];
    const float* E       = (const float*)d_in[2];
    const float* W_embed = (const float*)d_in[3];
    const float* b_embed = (const float*)d_in[4];
    const float* W_edge  = (const float*)d_in[5];
    const float* b_edge  = (const float*)d_in[6];
    const float* gk      = (const float*)d_in[7];
    const float* grk     = (const float*)d_in[8];
    const float* gb      = (const float*)d_in[9];
    const float* grb     = (const float*)d_in[10];
    float* out = (float*)d_out;

    // ws layout; H0/H1 have 257 rows (row 256 = sentinel zeros)
    float*  H0  = (float*)d_ws;                       // 257*64 floats
    float*  H1  = H0 + (ZROW + 1)*Fv;                 // 257*64 floats
    __bf16* Wf  = (__bf16*)(H1 + (ZROW + 1)*Fv);      // 256 KB
    __bf16* Ebf = Wf + 256*64*8;                      // 1 MB
    int*    ml_g  = (int*)(Ebf + (size_t)Bv*Nv*64*EDIM); // 64 KB
    int*    cnt_g = ml_g + Bv*Nv*64;                  // 1 KB
    int*    cnt2  = cnt_g + Bv*Nv;                    // 3 KB (3 x 256 arrival ctrs)
    float*  agg_g = (float*)(cnt2 + 3*256);           // 64 KB

    const dim3 rgrid(Bv*Nv, 8);

    prep_kernel<<<768, 64, 0, stream>>>(X, W_embed, b_embed, A, E, W_edge,
                                        H0, H1, Wf, Ebf, ml_g, cnt_g, cnt2);

    round_kernel<<<rgrid, 256, 0, stream>>>(H0, H1, Wf, b_edge, Ebf, ml_g, cnt_g,
                                            gk, grk, gb, grb, agg_g, cnt2 + 0);
    round_kernel<<<rgrid, 256, 0, stream>>>(H1, H0, Wf, b_edge, Ebf, ml_g, cnt_g,
                                            gk, grk, gb, grb, agg_g, cnt2 + 256);
    round_kernel<<<rgrid, 256, 0, stream>>>(H0, out, Wf, b_edge, Ebf, ml_g, cnt_g,
                                            gk, grk, gb, grb, agg_g, cnt2 + 512);
}

// Round 15
// 57.950 us; speedup vs baseline: 2.3226x; 2.3226x over previous
//
#include <hip/hip_runtime.h>
#include <math.h>

// Problem constants (B, N, F_IN, E_DIM, F, T) = (4, 64, 32, 32, 64, 3)
#define Bv   4
#define Nv   64
#define FIN  32
#define EDIM 32
#define Fv   64
#define NN   (Nv*Nv)
#define ZROW 256            // sentinel H row (always zero) for padded edges

typedef __bf16 bf16x8 __attribute__((ext_vector_type(8)));
typedef float  f32x4  __attribute__((ext_vector_type(4)));

__device__ __forceinline__ float sigmoidf_(float x) {
    return 1.f / (1.f + __expf(-x));
}

// ---------------------------------------------------------------------------
// One-time prep, fused: grid 768 x 64 threads.  (R9-proven, verbatim)
// ---------------------------------------------------------------------------
__global__ __launch_bounds__(64) void prep_kernel(
    const float* __restrict__ X, const float* __restrict__ W_embed,
    const float* __restrict__ b_embed, const float* __restrict__ A,
    const float* __restrict__ E, const float* __restrict__ W_edge,
    float* __restrict__ H0, float* __restrict__ H1,
    __bf16* __restrict__ Wf, __bf16* __restrict__ Ebf,
    int* __restrict__ ml_g, int* __restrict__ cnt_g)
{
    const int blk  = blockIdx.x;
    const int lane = threadIdx.x;

    if (blk < 256) {                       // ---- W_edge fragments ----
        const int nt = blk;
        const int kb = (lane >> 4) * 8;
        const int c  = nt*16 + (lane & 15);
        bf16x8 v;
        #pragma unroll
        for (int t = 0; t < 8; ++t)
            v[t] = (__bf16)W_edge[(kb + t)*4096 + c];
        *(bf16x8*)(Wf + ((size_t)(nt*64 + lane))*8) = v;
        if (blk == 0) {                    // zero sentinel rows
            H0[ZROW*Fv + lane] = 0.f;
            H1[ZROW*Fv + lane] = 0.f;
        }
    } else if (blk < 512) {                // ---- edge list + E rows ----
        const int bn = blk - 256;
        const int b  = bn >> 6;
        const int n  = bn & 63;
        __shared__ int ml[Nv];
        const float av = A[b*NN + n*Nv + lane];
        const unsigned long long mk = __ballot(av != 0.f);
        const int cnt = (int)__popcll(mk);
        if (av != 0.f) {
            const int pos = (int)__popcll(mk & ((1ull << lane) - 1ull));
            ml[pos] = lane;
        }
        __syncthreads();
        ml_g[bn*64 + lane] = (lane < cnt) ? (b*Nv + ml[lane]) : ZROW;
        if (lane == 0) cnt_g[bn] = cnt;
        __bf16 row[EDIM];
        if (lane < cnt) {
            const float* er = E + ((size_t)(b*NN + n*Nv + ml[lane]))*EDIM;
            #pragma unroll
            for (int t = 0; t < 8; ++t) {
                const float4 x = *(const float4*)(er + 4*t);
                row[4*t  ] = (__bf16)x.x; row[4*t+1] = (__bf16)x.y;
                row[4*t+2] = (__bf16)x.z; row[4*t+3] = (__bf16)x.w;
            }
        } else {
            #pragma unroll
            for (int e = 0; e < EDIM; ++e) row[e] = (__bf16)0.f;
        }
        __bf16* dst = Ebf + ((size_t)(bn*64 + lane))*EDIM;
        #pragma unroll
        for (int t = 0; t < 4; ++t)
            *(bf16x8*)(dst + 8*t) = *(bf16x8*)(row + 8*t);
    } else {                               // ---- embed ----
        const int bn = blk - 512;
        __shared__ float xs[FIN];
        if (lane < FIN) xs[lane] = X[bn*FIN + lane];
        __syncthreads();
        float acc = b_embed[lane];
        #pragma unroll
        for (int k = 0; k < FIN; ++k)
            acc = fmaf(xs[k], W_embed[k*Fv + lane], acc);
        H0[bn*Fv + lane] = fmaxf(acc, 0.f);
    }
}

// ---------------------------------------------------------------------------
// Message body, 4 i-slices per wave (R9 math; hu/af/ri amortized 2x).
// Block (bn,qq2) covers i in [qq2*16, qq2*16+16); wave w owns
// iA = qq2*16 + w*2, iA+1 and iB = iA+8, iB+1. Per u, the gathered hu
// values (qq-independent!) are loaded once and feed all 4 slices.
// ---------------------------------------------------------------------------
template<int MTN>
__device__ __forceinline__ void msg_body4(
    int bn, int qq2, int w, int lane,
    const float* __restrict__ Hin, const __bf16* __restrict__ Wf,
    const float* __restrict__ b_edge, const __bf16* __restrict__ Ebf,
    const int* __restrict__ ml_g, float* __restrict__ agg_g)
{
    const int c16 = lane & 15;
    const int rg  = (lane >> 4) * 4;
    const int kb  = (lane >> 4) * 8;

    bf16x8 af[MTN];
    int4   ri[MTN];
    #pragma unroll
    for (int mt = 0; mt < MTN; ++mt) {
        af[mt] = *(const bf16x8*)(Ebf + ((size_t)(bn*64 + mt*16 + c16))*EDIM + kb);
        ri[mt] = *(const int4*)(ml_g + bn*64 + mt*16 + rg);
    }

    const int iA = qq2*16 + w*2;
    const int iB = iA + 8;
    float pA0 = 0.f, pA1 = 0.f, pB0 = 0.f, pB1 = 0.f;

    #pragma unroll
    for (int u = 0; u < 4; ++u) {
        const int jc = u*16 + c16;
        float hu[MTN][4];
        #pragma unroll
        for (int mt = 0; mt < MTN; ++mt) {
            hu[mt][0] = Hin[ri[mt].x*Fv + jc];
            hu[mt][1] = Hin[ri[mt].y*Fv + jc];
            hu[mt][2] = Hin[ri[mt].z*Fv + jc];
            hu[mt][3] = Hin[ri[mt].w*Fv + jc];
        }
        #pragma unroll
        for (int half = 0; half < 2; ++half) {
            const int ibase = (half == 0) ? iA : iB;
            #pragma unroll
            for (int ii = 0; ii < 2; ++ii) {
                const int nt = (ibase + ii)*4 + u;
                const bf16x8 bf = *(const bf16x8*)(Wf + ((size_t)(nt*64 + lane))*8);
                const float  be = b_edge[nt*16 + c16];
                f32x4 cb; cb[0] = be; cb[1] = be; cb[2] = be; cb[3] = be;
                float acc = 0.f;
                #pragma unroll
                for (int mt = 0; mt < MTN; ++mt) {
                    f32x4 d = __builtin_amdgcn_mfma_f32_16x16x32_bf16(af[mt], bf, cb, 0, 0, 0);
                    acc = fmaf(fmaxf(d[0], 0.f), hu[mt][0], acc);
                    acc = fmaf(fmaxf(d[1], 0.f), hu[mt][1], acc);
                    acc = fmaf(fmaxf(d[2], 0.f), hu[mt][2], acc);
                    acc = fmaf(fmaxf(d[3], 0.f), hu[mt][3], acc);
                }
                if (half == 0) { if (ii == 0) pA0 += acc; else pA1 += acc; }
                else           { if (ii == 0) pB0 += acc; else pB1 += acc; }
            }
        }
    }
    #pragma unroll
    for (int off = 32; off > 0; off >>= 1) {
        pA0 += __shfl_xor(pA0, off);
        pA1 += __shfl_xor(pA1, off);
        pB0 += __shfl_xor(pB0, off);
        pB1 += __shfl_xor(pB1, off);
    }
    if (lane == 0) {
        agg_g[bn*Fv + iA]     = pA0;
        agg_g[bn*Fv + iA + 1] = pA1;
        agg_g[bn*Fv + iB]     = pB0;
        agg_g[bn*Fv + iB + 1] = pB1;
    }
}

// general single-node path (rare, cnt > 32): runtime mt loop, takes i0
__device__ __forceinline__ void msg_general(
    int bn, int Mt, int i0, int lane,
    const float* __restrict__ Hin, const __bf16* __restrict__ Wf,
    const float* __restrict__ b_edge, const __bf16* __restrict__ Ebf,
    const int* __restrict__ ml_g, float* __restrict__ agg_g)
{
    const int c16 = lane & 15;
    const int rg  = (lane >> 4) * 4;
    const int kb  = (lane >> 4) * 8;
    #pragma unroll
    for (int ii = 0; ii < 2; ++ii) {
        float part = 0.f;
        #pragma unroll 1
        for (int u = 0; u < 4; ++u) {
            const int jc = u*16 + c16;
            const int nt = (i0 + ii)*4 + u;
            const bf16x8 bf = *(const bf16x8*)(Wf + ((size_t)(nt*64 + lane))*8);
            const float  be = b_edge[nt*16 + c16];
            f32x4 cb; cb[0] = be; cb[1] = be; cb[2] = be; cb[3] = be;
            for (int mt = 0; mt < Mt; ++mt) {
                const bf16x8 a_ = *(const bf16x8*)(Ebf + ((size_t)(bn*64 + mt*16 + c16))*EDIM + kb);
                const int4 ri = *(const int4*)(ml_g + bn*64 + mt*16 + rg);
                f32x4 d = __builtin_amdgcn_mfma_f32_16x16x32_bf16(a_, bf, cb, 0, 0, 0);
                part = fmaf(fmaxf(d[0], 0.f), Hin[ri.x*Fv + jc], part);
                part = fmaf(fmaxf(d[1], 0.f), Hin[ri.y*Fv + jc], part);
                part = fmaf(fmaxf(d[2], 0.f), Hin[ri.z*Fv + jc], part);
                part = fmaf(fmaxf(d[3], 0.f), Hin[ri.w*Fv + jc], part);
            }
        }
        #pragma unroll
        for (int off = 32; off > 0; off >>= 1)
            part += __shfl_xor(part, off);
        if (lane == 0) agg_g[bn*Fv + i0 + ii] = part;
    }
}

// ---------------------------------------------------------------------------
// Message kernel: grid (256, 4), 256 threads = 4 waves, 4 slices/wave.
// ---------------------------------------------------------------------------
__global__ __launch_bounds__(256) void msg_kernel(
    const float* __restrict__ Hin, const __bf16* __restrict__ Wf,
    const float* __restrict__ b_edge, const __bf16* __restrict__ Ebf,
    const int* __restrict__ ml_g, const int* __restrict__ cnt_g,
    float* __restrict__ agg_g)
{
    const int bn   = blockIdx.x;
    const int qq2  = blockIdx.y;           // 0..3
    const int tid  = threadIdx.x;
    const int w    = tid >> 6;
    const int lane = tid & 63;

    const int cnt = cnt_g[bn];
    const int Mt  = (cnt == 0) ? 1 : ((cnt + 15) >> 4);   // block-uniform

    if (Mt <= 1) {
        msg_body4<1>(bn, qq2, w, lane, Hin, Wf, b_edge, Ebf, ml_g, agg_g);
    } else if (Mt == 2) {
        msg_body4<2>(bn, qq2, w, lane, Hin, Wf, b_edge, Ebf, ml_g, agg_g);
    } else {
        const int iA = qq2*16 + w*2;
        msg_general(bn, Mt, iA,     lane, Hin, Wf, b_edge, Ebf, ml_g, agg_g);
        msg_general(bn, Mt, iA + 8, lane, Hin, Wf, b_edge, Ebf, ml_g, agg_g);
    }
}

// ---------------------------------------------------------------------------
// Both GRU steps for one round. grid = B*N blocks, 192 threads. (R9 verbatim)
// ---------------------------------------------------------------------------
__global__ __launch_bounds__(192) void gru_kernel(
    const float* __restrict__ Hin, const float* __restrict__ agg_g,
    float* __restrict__ Hout,
    const float* __restrict__ gk, const float* __restrict__ grk,
    const float* __restrict__ gb, const float* __restrict__ grb)
{
    const int bn  = blockIdx.x;
    const int tid = threadIdx.x;   // 0..191

    __shared__ float h_old[Fv];
    __shared__ float aggs[Fv];
    __shared__ float h1[Fv];
    __shared__ float xg[3*Fv];
    __shared__ float hg[3*Fv];

    if (tid < Fv) {
        h_old[tid] = Hin[bn*Fv + tid];
        aggs[tid]  = agg_g[bn*Fv + tid];
    }
    __syncthreads();

    // step 1: h = 0, x = h_old (recurrent side is just the bias)
    {
        float a0 = 0.f, a1 = 0.f, a2 = 0.f, a3 = 0.f;
        #pragma unroll
        for (int k = 0; k < 16; ++k) {
            a0 = fmaf(h_old[k],      gk[(k     )*192 + tid], a0);
            a1 = fmaf(h_old[k + 16], gk[(k + 16)*192 + tid], a1);
            a2 = fmaf(h_old[k + 32], gk[(k + 32)*192 + tid], a2);
            a3 = fmaf(h_old[k + 48], gk[(k + 48)*192 + tid], a3);
        }
        xg[tid] = gb[tid] + ((a0 + a1) + (a2 + a3));
    }
    __syncthreads();
    if (tid < Fv) {
        float z    = sigmoidf_(xg[tid]       + grb[tid]);
        float r    = sigmoidf_(xg[64 + tid]  + grb[64 + tid]);
        float cand = tanhf    (xg[128 + tid] + r * grb[128 + tid]);
        h1[tid] = (1.f - z) * cand;          // z*h + (1-z)*cand with h=0
    }
    __syncthreads();

    // step 2: h = h1, x = agg
    {
        float x0 = 0.f, x1 = 0.f, x2 = 0.f, x3 = 0.f;
        float y0 = 0.f, y1 = 0.f, y2 = 0.f, y3 = 0.f;
        #pragma unroll
        for (int k = 0; k < 16; ++k) {
            x0 = fmaf(aggs[k],      gk [(k     )*192 + tid], x0);
            x1 = fmaf(aggs[k + 16], gk [(k + 16)*192 + tid], x1);
            x2 = fmaf(aggs[k + 32], gk [(k + 32)*192 + tid], x2);
            x3 = fmaf(aggs[k + 48], gk [(k + 48)*192 + tid], x3);
            y0 = fmaf(h1[k],        grk[(k     )*192 + tid], y0);
            y1 = fmaf(h1[k + 16],   grk[(k + 16)*192 + tid], y1);
            y2 = fmaf(h1[k + 32],   grk[(k + 32)*192 + tid], y2);
            y3 = fmaf(h1[k + 48],   grk[(k + 48)*192 + tid], y3);
        }
        xg[tid] = gb[tid]  + ((x0 + x1) + (x2 + x3));
        hg[tid] = grb[tid] + ((y0 + y1) + (y2 + y3));
    }
    __syncthreads();
    if (tid < Fv) {
        float z    = sigmoidf_(xg[tid]       + hg[tid]);
        float r    = sigmoidf_(xg[64 + tid]  + hg[64 + tid]);
        float cand = tanhf    (xg[128 + tid] + r * hg[128 + tid]);
        Hout[bn*Fv + tid] = z * h1[tid] + (1.f - z) * cand;
    }
}

extern "C" void kernel_launch(void* const* d_in, const int* in_sizes, int n_in,
                              void* d_out, int out_size, void* d_ws, size_t ws_size,
                              hipStream_t stream)
{
    const float* X       = (const float*)d_in[0];
    const float* A       = (const float*)d_in[1];
    const float* E       = (const float*)d_in[2];
    const float* W_embed = (const float*)d_in[3];
    const float* b_embed = (const float*)d_in[4];
    const float* W_edge  = (const float*)d_in[5];
    const float* b_edge  = (const float*)d_in[6];
    const float* gk      = (const float*)d_in[7];
    const float* grk     = (const float*)d_in[8];
    const float* gb      = (const float*)d_in[9];
    const float* grb     = (const float*)d_in[10];
    float* out = (float*)d_out;

    // ws layout; H0/H1 have 257 rows (row 256 = sentinel zeros)
    float*  H0  = (float*)d_ws;                       // 257*64 floats
    float*  H1  = H0 + (ZROW + 1)*Fv;                 // 257*64 floats
    __bf16* Wf  = (__bf16*)(H1 + (ZROW + 1)*Fv);      // 256 KB
    __bf16* Ebf = Wf + 256*64*8;                      // 1 MB
    int*    ml_g  = (int*)(Ebf + (size_t)Bv*Nv*64*EDIM); // 64 KB
    int*    cnt_g = ml_g + Bv*Nv*64;                  // 1 KB

    const dim3 mgrid(Bv*Nv, 4);

    prep_kernel<<<768, 64, 0, stream>>>(X, W_embed, b_embed, A, E, W_edge,
                                        H0, H1, Wf, Ebf, ml_g, cnt_g);

    // round 1: H0 -> H1, agg scratch = out (dead until the end)
    msg_kernel<<<mgrid, 256, 0, stream>>>(H0, Wf, b_edge, Ebf, ml_g, cnt_g, out);
    gru_kernel<<<Bv*Nv, 192, 0, stream>>>(H0, out, H1, gk, grk, gb, grb);
    // round 2: H1 -> H0, agg scratch = out
    msg_kernel<<<mgrid, 256, 0, stream>>>(H1, Wf, b_edge, Ebf, ml_g, cnt_g, out);
    gru_kernel<<<Bv*Nv, 192, 0, stream>>>(H1, out, H0, gk, grk, gb, grb);
    // round 3: H0 -> out, agg scratch = H1 (dead after round 2)
    msg_kernel<<<mgrid, 256, 0, stream>>>(H0, Wf, b_edge, Ebf, ml_g, cnt_g, H1);
    gru_kernel<<<Bv*Nv, 192, 0, stream>>>(H0, H1, out, gk, grk, gb, grb);
}

// Round 16
// 48.070 us; speedup vs baseline: 2.8000x; 1.2055x over previous
//
#include <hip/hip_runtime.h>
#include <math.h>

// Problem constants (B, N, F_IN, E_DIM, F, T) = (4, 64, 32, 32, 64, 3)
#define Bv   4
#define Nv   64
#define FIN  32
#define EDIM 32
#define Fv   64
#define NN   (Nv*Nv)
#define ZROW 256            // sentinel H row (always zero) for padded edges

typedef __bf16 bf16x8 __attribute__((ext_vector_type(8)));
typedef float  f32x4  __attribute__((ext_vector_type(4)));

__device__ __forceinline__ float sigmoidf_(float x) {
    return 1.f / (1.f + __expf(-x));
}

// ---------------------------------------------------------------------------
// One-time prep, fused: grid 768 x 64 threads.
//   blk <  256 : W_edge -> bf16 B-fragments Wf[nt*64+lane][8]
//                (blk 0 also zeroes the sentinel row of H0 and H1)
//   blk <  512 : per-node edge list (GLOBAL H-row ids, pad->ZROW) and
//                E -> bf16 A-fragment rows (zero-padded) Ebf[bn][64][32]
//   blk >= 512 : embed  H0 = relu(X @ W_embed + b_embed)
// ---------------------------------------------------------------------------
__global__ __launch_bounds__(64) void prep_kernel(
    const float* __restrict__ X, const float* __restrict__ W_embed,
    const float* __restrict__ b_embed, const float* __restrict__ A,
    const float* __restrict__ E, const float* __restrict__ W_edge,
    float* __restrict__ H0, float* __restrict__ H1,
    __bf16* __restrict__ Wf, __bf16* __restrict__ Ebf,
    int* __restrict__ ml_g, int* __restrict__ cnt_g)
{
    const int blk  = blockIdx.x;
    const int lane = threadIdx.x;

    if (blk < 256) {                       // ---- W_edge fragments ----
        const int nt = blk;
        const int kb = (lane >> 4) * 8;
        const int c  = nt*16 + (lane & 15);
        bf16x8 v;
        #pragma unroll
        for (int t = 0; t < 8; ++t)
            v[t] = (__bf16)W_edge[(kb + t)*4096 + c];
        *(bf16x8*)(Wf + ((size_t)(nt*64 + lane))*8) = v;
        if (blk == 0) {                    // zero sentinel rows
            H0[ZROW*Fv + lane] = 0.f;
            H1[ZROW*Fv + lane] = 0.f;
        }
    } else if (blk < 512) {                // ---- edge list + E rows ----
        const int bn = blk - 256;
        const int b  = bn >> 6;
        const int n  = bn & 63;
        __shared__ int ml[Nv];

        // lane-parallel compaction: block = exactly one wave (64 threads)
        const float av = A[b*NN + n*Nv + lane];
        const unsigned long long mk = __ballot(av != 0.f);
        const int cnt = (int)__popcll(mk);
        if (av != 0.f) {
            const int pos = (int)__popcll(mk & ((1ull << lane) - 1ull));
            ml[pos] = lane;
        }
        __syncthreads();

        ml_g[bn*64 + lane] = (lane < cnt) ? (b*Nv + ml[lane]) : ZROW;
        if (lane == 0) cnt_g[bn] = cnt;

        __bf16 row[EDIM];
        if (lane < cnt) {
            const float* er = E + ((size_t)(b*NN + n*Nv + ml[lane]))*EDIM;
            #pragma unroll
            for (int t = 0; t < 8; ++t) {
                const float4 x = *(const float4*)(er + 4*t);
                row[4*t  ] = (__bf16)x.x; row[4*t+1] = (__bf16)x.y;
                row[4*t+2] = (__bf16)x.z; row[4*t+3] = (__bf16)x.w;
            }
        } else {
            #pragma unroll
            for (int e = 0; e < EDIM; ++e) row[e] = (__bf16)0.f;
        }
        __bf16* dst = Ebf + ((size_t)(bn*64 + lane))*EDIM;
        #pragma unroll
        for (int t = 0; t < 4; ++t)
            *(bf16x8*)(dst + 8*t) = *(bf16x8*)(row + 8*t);
    } else {                               // ---- embed ----
        const int bn = blk - 512;
        __shared__ float xs[FIN];
        if (lane < FIN) xs[lane] = X[bn*FIN + lane];
        __syncthreads();
        float acc = b_embed[lane];
        #pragma unroll
        for (int k = 0; k < FIN; ++k)
            acc = fmaf(xs[k], W_embed[k*Fv + lane], acc);
        H0[bn*Fv + lane] = fmaxf(acc, 0.f);
    }
}

// ---------------------------------------------------------------------------
// Message phase via MFMA — LDS-free, barrier-free.  (R6-proven, unchanged)
// grid = (B*N, 8), 256 threads = 4 waves. Wave w of block (bn,qq) owns
// i0 = qq*8 + w*2 and i0+1. u-outer: gathered H values loaded once per u,
// reused by both i-slices; bias rides the MFMA C-operand.
// ---------------------------------------------------------------------------
template<int MTN>
__device__ __forceinline__ void msg_body(
    int bn, int qq, int w, int lane,
    const float* __restrict__ Hin, const __bf16* __restrict__ Wf,
    const float* __restrict__ b_edge, const __bf16* __restrict__ Ebf,
    const int* __restrict__ ml_g, float* __restrict__ agg_g)
{
    const int c16 = lane & 15;
    const int rg  = (lane >> 4) * 4;
    const int kb  = (lane >> 4) * 8;

    bf16x8 af[MTN];
    int4   ri[MTN];
    #pragma unroll
    for (int mt = 0; mt < MTN; ++mt) {
        af[mt] = *(const bf16x8*)(Ebf + ((size_t)(bn*64 + mt*16 + c16))*EDIM + kb);
        ri[mt] = *(const int4*)(ml_g + bn*64 + mt*16 + rg);
    }

    const int i0 = qq*8 + w*2;
    float p0 = 0.f, p1 = 0.f;

    #pragma unroll
    for (int u = 0; u < 4; ++u) {
        const int jc = u*16 + c16;
        float hu[MTN][4];
        #pragma unroll
        for (int mt = 0; mt < MTN; ++mt) {
            hu[mt][0] = Hin[ri[mt].x*Fv + jc];
            hu[mt][1] = Hin[ri[mt].y*Fv + jc];
            hu[mt][2] = Hin[ri[mt].z*Fv + jc];
            hu[mt][3] = Hin[ri[mt].w*Fv + jc];
        }
        #pragma unroll
        for (int ii = 0; ii < 2; ++ii) {
            const int nt = (i0 + ii)*4 + u;
            const bf16x8 bf = *(const bf16x8*)(Wf + ((size_t)(nt*64 + lane))*8);
            const float  be = b_edge[nt*16 + c16];
            f32x4 cb; cb[0] = be; cb[1] = be; cb[2] = be; cb[3] = be;
            float acc = 0.f;
            #pragma unroll
            for (int mt = 0; mt < MTN; ++mt) {
                f32x4 d = __builtin_amdgcn_mfma_f32_16x16x32_bf16(af[mt], bf, cb, 0, 0, 0);
                acc = fmaf(fmaxf(d[0], 0.f), hu[mt][0], acc);
                acc = fmaf(fmaxf(d[1], 0.f), hu[mt][1], acc);
                acc = fmaf(fmaxf(d[2], 0.f), hu[mt][2], acc);
                acc = fmaf(fmaxf(d[3], 0.f), hu[mt][3], acc);
            }
            if (ii == 0) p0 += acc; else p1 += acc;
        }
    }
    #pragma unroll
    for (int off = 32; off > 0; off >>= 1) {
        p0 += __shfl_xor(p0, off);
        p1 += __shfl_xor(p1, off);
    }
    if (lane == 0) {
        agg_g[bn*Fv + i0]     = p0;
        agg_g[bn*Fv + i0 + 1] = p1;
    }
}

__global__ __launch_bounds__(256) void msg_kernel(
    const float* __restrict__ Hin, const __bf16* __restrict__ Wf,
    const float* __restrict__ b_edge, const __bf16* __restrict__ Ebf,
    const int* __restrict__ ml_g, const int* __restrict__ cnt_g,
    float* __restrict__ agg_g)
{
    const int bn   = blockIdx.x;
    const int qq   = blockIdx.y;
    const int tid  = threadIdx.x;
    const int w    = tid >> 6;
    const int lane = tid & 63;

    const int cnt = cnt_g[bn];
    const int Mt  = (cnt == 0) ? 1 : ((cnt + 15) >> 4);   // block-uniform

    if (Mt <= 1) {
        msg_body<1>(bn, qq, w, lane, Hin, Wf, b_edge, Ebf, ml_g, agg_g);
    } else if (Mt == 2) {
        msg_body<2>(bn, qq, w, lane, Hin, Wf, b_edge, Ebf, ml_g, agg_g);
    } else {
        // rare path (cnt > 32): runtime mt loop, minimal live registers
        const int c16 = lane & 15;
        const int rg  = (lane >> 4) * 4;
        const int kb  = (lane >> 4) * 8;
        const int i0  = qq*8 + w*2;
        #pragma unroll
        for (int ii = 0; ii < 2; ++ii) {
            float part = 0.f;
            #pragma unroll 1
            for (int u = 0; u < 4; ++u) {
                const int jc = u*16 + c16;
                const int nt = (i0 + ii)*4 + u;
                const bf16x8 bf = *(const bf16x8*)(Wf + ((size_t)(nt*64 + lane))*8);
                const float  be = b_edge[nt*16 + c16];
                f32x4 cb; cb[0] = be; cb[1] = be; cb[2] = be; cb[3] = be;
                for (int mt = 0; mt < Mt; ++mt) {
                    const bf16x8 a_ = *(const bf16x8*)(Ebf + ((size_t)(bn*64 + mt*16 + c16))*EDIM + kb);
                    const int4 ri = *(const int4*)(ml_g + bn*64 + mt*16 + rg);
                    f32x4 d = __builtin_amdgcn_mfma_f32_16x16x32_bf16(a_, bf, cb, 0, 0, 0);
                    part = fmaf(fmaxf(d[0], 0.f), Hin[ri.x*Fv + jc], part);
                    part = fmaf(fmaxf(d[1], 0.f), Hin[ri.y*Fv + jc], part);
                    part = fmaf(fmaxf(d[2], 0.f), Hin[ri.z*Fv + jc], part);
                    part = fmaf(fmaxf(d[3], 0.f), Hin[ri.w*Fv + jc], part);
                }
            }
            #pragma unroll
            for (int off = 32; off > 0; off >>= 1)
                part += __shfl_xor(part, off);
            if (lane == 0) agg_g[bn*Fv + i0 + ii] = part;
        }
    }
}

// ---------------------------------------------------------------------------
// Both GRU steps for one round. grid = B*N blocks, 192 threads.  (unchanged)
// ---------------------------------------------------------------------------
__global__ __launch_bounds__(192) void gru_kernel(
    const float* __restrict__ Hin, const float* __restrict__ agg_g,
    float* __restrict__ Hout,
    const float* __restrict__ gk, const float* __restrict__ grk,
    const float* __restrict__ gb, const float* __restrict__ grb)
{
    const int bn  = blockIdx.x;
    const int tid = threadIdx.x;   // 0..191

    __shared__ float h_old[Fv];
    __shared__ float aggs[Fv];
    __shared__ float h1[Fv];
    __shared__ float xg[3*Fv];
    __shared__ float hg[3*Fv];

    if (tid < Fv) {
        h_old[tid] = Hin[bn*Fv + tid];
        aggs[tid]  = agg_g[bn*Fv + tid];
    }
    __syncthreads();

    // step 1: h = 0, x = h_old (recurrent side is just the bias)
    {
        float a0 = 0.f, a1 = 0.f, a2 = 0.f, a3 = 0.f;
        #pragma unroll
        for (int k = 0; k < 16; ++k) {
            a0 = fmaf(h_old[k],      gk[(k     )*192 + tid], a0);
            a1 = fmaf(h_old[k + 16], gk[(k + 16)*192 + tid], a1);
            a2 = fmaf(h_old[k + 32], gk[(k + 32)*192 + tid], a2);
            a3 = fmaf(h_old[k + 48], gk[(k + 48)*192 + tid], a3);
        }
        xg[tid] = gb[tid] + ((a0 + a1) + (a2 + a3));
    }
    __syncthreads();
    if (tid < Fv) {
        float z    = sigmoidf_(xg[tid]       + grb[tid]);
        float r    = sigmoidf_(xg[64 + tid]  + grb[64 + tid]);
        float cand = tanhf    (xg[128 + tid] + r * grb[128 + tid]);
        h1[tid] = (1.f - z) * cand;          // z*h + (1-z)*cand with h=0
    }
    __syncthreads();

    // step 2: h = h1, x = agg
    {
        float x0 = 0.f, x1 = 0.f, x2 = 0.f, x3 = 0.f;
        float y0 = 0.f, y1 = 0.f, y2 = 0.f, y3 = 0.f;
        #pragma unroll
        for (int k = 0; k < 16; ++k) {
            x0 = fmaf(aggs[k],      gk [(k     )*192 + tid], x0);
            x1 = fmaf(aggs[k + 16], gk [(k + 16)*192 + tid], x1);
            x2 = fmaf(aggs[k + 32], gk [(k + 32)*192 + tid], x2);
            x3 = fmaf(aggs[k + 48], gk [(k + 48)*192 + tid], x3);
            y0 = fmaf(h1[k],        grk[(k     )*192 + tid], y0);
            y1 = fmaf(h1[k + 16],   grk[(k + 16)*192 + tid], y1);
            y2 = fmaf(h1[k + 32],   grk[(k + 32)*192 + tid], y2);
            y3 = fmaf(h1[k + 48],   grk[(k + 48)*192 + tid], y3);
        }
        xg[tid] = gb[tid]  + ((x0 + x1) + (x2 + x3));
        hg[tid] = grb[tid] + ((y0 + y1) + (y2 + y3));
    }
    __syncthreads();
    if (tid < Fv) {
        float z    = sigmoidf_(xg[tid]       + hg[tid]);
        float r    = sigmoidf_(xg[64 + tid]  + hg[64 + tid]);
        float cand = tanhf    (xg[128 + tid] + r * hg[128 + tid]);
        Hout[bn*Fv + tid] = z * h1[tid] + (1.f - z) * cand;
    }
}

extern "C" void kernel_launch(void* const* d_in, const int* in_sizes, int n_in,
                              void* d_out, int out_size, void* d_ws, size_t ws_size,
                              hipStream_t stream)
{
    const float* X       = (const float*)d_in[0];
    const float* A       = (const float*)d_in[1];
    const float* E       = (const float*)d_in[2];
    const float* W_embed = (const float*)d_in[3];
    const float* b_embed = (const float*)d_in[4];
    const float* W_edge  = (const float*)d_in[5];
    const float* b_edge  = (const float*)d_in[6];
    const float* gk      = (const float*)d_in[7];
    const float* grk     = (const float*)d_in[8];
    const float* gb      = (const float*)d_in[9];
    const float* grb     = (const float*)d_in[10];
    float* out = (float*)d_out;

    // ws layout; H0/H1 have 257 rows (row 256 = sentinel zeros)
    float*  H0  = (float*)d_ws;                       // 257*64 floats
    float*  H1  = H0 + (ZROW + 1)*Fv;                 // 257*64 floats
    __bf16* Wf  = (__bf16*)(H1 + (ZROW + 1)*Fv);      // 256 KB
    __bf16* Ebf = Wf + 256*64*8;                      // 1 MB
    int*    ml_g  = (int*)(Ebf + (size_t)Bv*Nv*64*EDIM); // 64 KB
    int*    cnt_g = ml_g + Bv*Nv*64;                  // 1 KB

    const dim3 mgrid(Bv*Nv, 8);

    prep_kernel<<<768, 64, 0, stream>>>(X, W_embed, b_embed, A, E, W_edge,
                                        H0, H1, Wf, Ebf, ml_g, cnt_g);

    // round 1: H0 -> H1, agg scratch = out (dead until the end)
    msg_kernel<<<mgrid, 256, 0, stream>>>(H0, Wf, b_edge, Ebf, ml_g, cnt_g, out);
    gru_kernel<<<Bv*Nv, 192, 0, stream>>>(H0, out, H1, gk, grk, gb, grb);
    // round 2: H1 -> H0, agg scratch = out
    msg_kernel<<<mgrid, 256, 0, stream>>>(H1, Wf, b_edge, Ebf, ml_g, cnt_g, out);
    gru_kernel<<<Bv*Nv, 192, 0, stream>>>(H1, out, H0, gk, grk, gb, grb);
    // round 3: H0 -> out, agg scratch = H1 (dead after round 2)
    msg_kernel<<<mgrid, 256, 0, stream>>>(H0, Wf, b_edge, Ebf, ml_g, cnt_g, H1);
    gru_kernel<<<Bv*Nv, 192, 0, stream>>>(H0, H1, out, gk, grk, gb, grb);
}